// Round 12
// baseline (285.924 us; speedup 1.0000x reference)
//
#include <hip/hip_runtime.h>
#include <stdint.h>

// Problem constants (fixed by the reference): B=8, H=W=64, C=256
#define CC 256
#define NN 4096           // H*W
#define MM 2048           // NN/2 (pooled)
#define BB 8
#define NROWS (BB*NN)     // 32768 query rows
#define PROWS (BB*MM)     // 16384 pooled rows

typedef __attribute__((ext_vector_type(8))) short    short8;   // 8 bf16
typedef __attribute__((ext_vector_type(8))) _Float16 half8;    // 8 fp16
typedef __attribute__((ext_vector_type(4))) float    float4v;

__device__ __forceinline__ unsigned short f2bf(float f) {
    unsigned int u = __float_as_uint(f);
    u += 0x7fffu + ((u >> 16) & 1u);
    return (unsigned short)(u >> 16);
}
__device__ __forceinline__ float bf2f(unsigned short h) {
    return __uint_as_float(((unsigned int)h) << 16);
}
__device__ __forceinline__ unsigned short f2h(float f) {
    union { _Float16 h; unsigned short u; } cv; cv.h = (_Float16)f; return cv.u;
}
__device__ __forceinline__ float h2f(unsigned short u) {
    union { _Float16 h; unsigned short u; } cv; cv.u = u; return (float)cv.h;
}

// ---------------------------------------------------------------------------
// xsplit: x (fp32) -> x_hi/x_lo (bf16 split), elementwise, once.
// ---------------------------------------------------------------------------
__global__ __launch_bounds__(256) void xsplit_kernel(
    const float* __restrict__ x,
    unsigned short* __restrict__ x_hi,
    unsigned short* __restrict__ x_lo)
{
    const size_t i = ((size_t)blockIdx.x*256 + threadIdx.x) * 8;
    float4v a0 = *(const float4v*)(x + i);
    float4v a1 = *(const float4v*)(x + i + 4);
    short8 h, l;
    #pragma unroll
    for (int j = 0; j < 4; ++j) {
        unsigned short h0 = f2bf(a0[j]);
        h[j]   = (short)h0; l[j]   = (short)f2bf(a0[j] - bf2f(h0));
        unsigned short h1 = f2bf(a1[j]);
        h[4+j] = (short)h1; l[4+j] = (short)f2bf(a1[j] - bf2f(h1));
    }
    *(short8*)(x_hi + i) = h;
    *(short8*)(x_lo + i) = l;
}

// ---------------------------------------------------------------------------
// wsplit: transpose + bf16 hi/lo split the three 256x256 weights once.
// ---------------------------------------------------------------------------
__global__ void wsplit_kernel(const float* __restrict__ w_theta,
                              const float* __restrict__ w_phi,
                              const float* __restrict__ w_g,
                              unsigned short* __restrict__ wT_hi,
                              unsigned short* __restrict__ wT_lo)
{
    __shared__ float tile[64][65];
    const int widx = blockIdx.z;
    const int kt = blockIdx.x, ct = blockIdx.y;
    const float* w = (widx == 0) ? w_theta : (widx == 1) ? w_phi : w_g;
    const int t  = threadIdx.x;
    const int tc = t & 63, tr = t >> 6;
    #pragma unroll
    for (int i = 0; i < 16; ++i) {
        const int lk = tr*16 + i;
        tile[lk][tc] = w[(size_t)(kt*64 + lk)*CC + ct*64 + tc];
    }
    __syncthreads();
    #pragma unroll
    for (int i = 0; i < 16; ++i) {
        const int lc = tr*16 + i;
        float v = tile[tc][lc];
        const int c = ct*64 + lc, k = kt*64 + tc;
        unsigned short hh = f2bf(v);
        size_t o = ((size_t)widx*CC + c)*CC + k;
        wT_hi[o] = hh;
        wT_lo[o] = f2bf(v - bf2f(hh));
    }
}

// ---------------------------------------------------------------------------
// proj_kernel v7 (verified in R9): g in MFMA B-FRAGMENT ORDER; theta/phi as v6.
// ---------------------------------------------------------------------------
__global__ __launch_bounds__(256, 4) void proj_kernel(
    const unsigned short* __restrict__ x_hi,
    const unsigned short* __restrict__ x_lo,
    const unsigned short* __restrict__ wT_hi,
    const unsigned short* __restrict__ wT_lo,
    unsigned short* __restrict__ th,
    unsigned short* __restrict__ ph,
    unsigned short* __restrict__ g_f)
{
    __shared__ unsigned short wt_hi[64*136];   // [64 cols][128 k + pad]
    __shared__ unsigned short wt_lo[64*136];

    const int tid  = threadIdx.x;
    const int rb   = blockIdx.x & 511;         // row-block (XCD = rb%8)
    const int cv   = blockIdx.x >> 9;          // 0..11 col-variant
    const int r0   = rb * 64;
    const int widx = cv >> 2;
    const int wc0  = (cv & 3) * 64;
    const unsigned short* wThp = wT_hi + ((size_t)widx*CC + wc0)*CC;
    const unsigned short* wTlp = wT_lo + ((size_t)widx*CC + wc0)*CC;
    const bool split3 = (widx < 2);            // theta/phi 3-pass; g 1-pass

    const int wv   = tid >> 6;
    const int lane = tid & 63;
    const int quad = lane >> 4;
    const int l15  = lane & 15;
    const int arow = r0 + wv*16 + l15;
    const unsigned short* axh = x_hi + (size_t)arow*CC + quad*8;
    const unsigned short* axl = x_lo + (size_t)arow*CC + quad*8;

    float4v acc[4];
    #pragma unroll
    for (int nf = 0; nf < 4; ++nf) acc[nf] = (float4v){0.f,0.f,0.f,0.f};

    for (int h = 0; h < 2; ++h) {
        __syncthreads();
        {   // stage pre-split W^T tile [64 cols][128 k] (pure copy)
            const int j    = tid & 63;
            const int kseg = tid >> 6;
            const size_t base = (size_t)j*CC + h*128 + kseg*32;
            const unsigned short* sh = wThp + base;
            unsigned short* dh = &wt_hi[j*136 + kseg*32];
            #pragma unroll
            for (int u = 0; u < 4; ++u)
                *(uint4*)(dh + u*8) = *(const uint4*)(sh + u*8);
            if (split3) {
                const unsigned short* sl = wTlp + base;
                unsigned short* dl = &wt_lo[j*136 + kseg*32];
                #pragma unroll
                for (int u = 0; u < 4; ++u)
                    *(uint4*)(dl + u*8) = *(const uint4*)(sl + u*8);
            }
        }
        __syncthreads();

        #pragma unroll
        for (int ks = 0; ks < 4; ++ks) {
            short8 a_hi = *(const short8*)(axh + h*128 + ks*32);
            short8 a_lo;
            if (split3) a_lo = *(const short8*)(axl + h*128 + ks*32);
            #pragma unroll
            for (int nf = 0; nf < 4; ++nf) {
                const int wrow = nf*16 + l15;
                short8 b_hi = *(const short8*)&wt_hi[wrow*136 + ks*32 + quad*8];
                acc[nf] = __builtin_amdgcn_mfma_f32_16x16x32_bf16(a_hi, b_hi, acc[nf], 0,0,0);
                if (split3) {
                    short8 b_lo = *(const short8*)&wt_lo[wrow*136 + ks*32 + quad*8];
                    acc[nf] = __builtin_amdgcn_mfma_f32_16x16x32_bf16(a_hi, b_lo, acc[nf], 0,0,0);
                    acc[nf] = __builtin_amdgcn_mfma_f32_16x16x32_bf16(a_lo, b_hi, acc[nf], 0,0,0);
                }
            }
        }
    }

    const int rowbase = r0 + wv*16 + quad*4;
    if (widx == 0) {                           // theta: unpooled, fp16 single
        #pragma unroll
        for (int nf = 0; nf < 4; ++nf) {
            const int c = wc0 + nf*16 + l15;
            #pragma unroll
            for (int r = 0; r < 4; ++r)
                th[(size_t)(rowbase + r)*CC + c] = f2h(acc[nf][r]);
        }
    } else if (widx == 1) {                    // phi: pool row pairs, fp16
        #pragma unroll
        for (int nf = 0; nf < 4; ++nf) {
            const int c = wc0 + nf*16 + l15;
            #pragma unroll
            for (int rp = 0; rp < 2; ++rp) {
                float v = fmaxf(acc[nf][2*rp], acc[nf][2*rp+1]);
                const int prow = rowbase/2 + rp;   // rowbase even -> exact
                ph[(size_t)prow*CC + c] = f2h(v);
            }
        }
    } else {                                   // g: pool, bf16, FRAG ORDER
        #pragma unroll
        for (int nf = 0; nf < 4; ++nf) {
            const int c = wc0 + nf*16 + l15;
            const int ct = c >> 4;             // col-tile 0..15
            const int c15 = c & 15;
            #pragma unroll
            for (int rp = 0; rp < 2; ++rp) {
                float v = fmaxf(acc[nf][2*rp], acc[nf][2*rp+1]);
                const int prow = rowbase/2 + rp;
                const int b  = prow >> 11;
                const int m  = prow & 2047;    // key index within batch
                const int kt = m >> 5;         // 32-key tile
                const int km = m & 31;
                const int lane_t = (km >> 3)*16 + c15;
                const int j = km & 7;
                g_f[(((size_t)(b*64 + kt)*16 + ct)*64 + lane_t)*8 + j] = f2bf(v);
            }
        }
    }
}

// ---------------------------------------------------------------------------
// phimean: per-batch column mean of phi; 512 blocks (32 rows each).
// ---------------------------------------------------------------------------
__global__ void phimean_kernel(const unsigned short* __restrict__ ph,
                               float* __restrict__ phbar)
{
    const int b = blockIdx.x >> 6, chunk = blockIdx.x & 63;
    const int c = threadIdx.x;
    const size_t base = ((size_t)b*MM + chunk*32)*CC + c;
    float s = 0.f;
    for (int r = 0; r < 32; ++r) s += h2f(ph[base + (size_t)r*CC]);
    atomicAdd(&phbar[b*CC + c], s * (1.0f/MM));
}

// ---------------------------------------------------------------------------
// attn_kernel v16: SWAPPED-OPERAND S (S^T = mfma(phi, theta)) -> each lane
// owns P for one q-row -> P->PV handoff IN REGISTERS (8 shfl + 4 selects),
// killing: s_p LDS exchange, lgkmcnt(0) stall, ones-MFMA, and ONE of the two
// barriers. PV = wave's own 16 q-rows x all 256 cols (pure-reg, before the
// staging barrier). Same math per element; l = same bf16 p values summed.
//  - S^T operands: phi frag is a valid A-frag, theta frag a valid B-frag
//    (identical per-lane data as v15's verified b0/t_hi loads).
//  - keeps v15 coalesced staging + R9 frag-ordered g + XCD affinity.
// ---------------------------------------------------------------------------
__global__ __launch_bounds__(256, 2) void attn_kernel(
    const float* __restrict__ x,
    const unsigned short* __restrict__ th,
    const unsigned short* __restrict__ ph,
    const unsigned short* __restrict__ g_f,
    const float* __restrict__ phbar,
    float* __restrict__ out)
{
    __shared__ unsigned short s_ph[2][32*264]; // phi dbuf fp16, padded rows

    const int tid  = threadIdx.x;
    const int bb   = blockIdx.x & 7;           // batch == XCD (L2 affinity)
    const int qt   = blockIdx.x >> 3;          // q-tile within batch
    const int q0   = bb*NN + qt*64;
    const int b    = bb;
    const int wv   = tid >> 6;
    const int lane = tid & 63;
    const int quad = lane >> 4;
    const int l15  = lane & 15;

    // coalesced staging geometry (v15): instr u, thread tid owns chunk u*256+tid
    const size_t phbase = (size_t)b * MM * CC;
    const unsigned short* stsrc = ph + phbase + (size_t)tid*8;
    const int ldsbase = (tid >> 5)*264 + (tid & 31)*8;

    // theta frags (fp16) for this wave's 16 q-rows; q = l15 per lane
    half8 t_hi[8];
    {
        const unsigned short* bh = th + (size_t)(q0 + wv*16 + l15)*CC;
        #pragma unroll
        for (int ks = 0; ks < 8; ++ks)
            t_hi[ks] = *(const half8*)(bh + ks*32 + quad*8);
    }

    // shift: per-lane scalar for q = l15 (S^T cols are q = l15)
    float sh;
    {
        float sp = 0.f;
        #pragma unroll
        for (int ks = 0; ks < 8; ++ks) {
            const int k0 = ks*32 + quad*8;
            float4v m0 = *(const float4v*)&phbar[b*CC + k0];
            float4v m1 = *(const float4v*)&phbar[b*CC + k0 + 4];
            #pragma unroll
            for (int j = 0; j < 4; ++j) {
                sp += (float)t_hi[ks][j]   * m0[j];
                sp += (float)t_hi[ks][4+j] * m1[j];
            }
        }
        sp += __shfl_xor(sp, 16);
        sp += __shfl_xor(sp, 32);
        sh = sp + 128.f;
    }

    // O: this wave's 16 q-rows x ALL 256 cols (16 col-tiles)
    float4v O[16];
    #pragma unroll
    for (int ct = 0; ct < 16; ++ct) O[ct] = (float4v){0.f,0.f,0.f,0.f};
    float laccum = 0.f;

    // frag-ordered g base (R9): per-lane 16B inside each 1KB frag
    const unsigned short* glf = g_f + (size_t)b*MM*CC + (size_t)lane*8;

    // prologue: stage tile 0 into buf 0 (coalesced)
    {
        #pragma unroll
        for (int u = 0; u < 4; ++u)
            *(uint4*)(&s_ph[0][ldsbase + u*2112]) =
                *(const uint4*)(stsrc + u*2048);
    }
    __syncthreads();

    const int srcb = ((quad & 1) << 5) + l15;   // transpose source lane (even quad)

    for (int kt = 0; kt < 64; ++kt) {
        const int cur = kt & 1;

        // issue next-tile phi loads early (coalesced)
        uint4 stg[4];
        if (kt < 63) {
            const unsigned short* sn = stsrc + (size_t)(kt + 1)*8192;
            #pragma unroll
            for (int u = 0; u < 4; ++u)
                stg[u] = *(const uint4*)(sn + u*2048);
        }
        // issue this tile's 16 g frags early (each ONE coalesced b128)
        short8 gf[16];
        #pragma unroll
        for (int ct = 0; ct < 16; ++ct)
            gf[ct] = *(const short8*)(glf + (size_t)(kt*16 + ct)*512);

        // S^T = phi @ theta^T: lane -> S^T[key=quad*4+r][q=l15]
        float4v S0T = (float4v){0.f,0.f,0.f,0.f};   // keys 0..15
        float4v S1T = (float4v){0.f,0.f,0.f,0.f};   // keys 16..31
        #pragma unroll
        for (int ks = 0; ks < 8; ++ks) {
            half8 b0 = *(const half8*)&s_ph[cur][( 0 + l15)*264 + ks*32 + quad*8];
            half8 b1 = *(const half8*)&s_ph[cur][(16 + l15)*264 + ks*32 + quad*8];
            S0T = __builtin_amdgcn_mfma_f32_16x16x32_f16(b0, t_hi[ks], S0T, 0,0,0);
            S1T = __builtin_amdgcn_mfma_f32_16x16x32_f16(b1, t_hi[ks], S1T, 0,0,0);
        }

        // p = exp(clamp(S - sh)) ; pack bf16 pairs (consecutive keys)
        float e0[4], e1[4];
        #pragma unroll
        for (int r = 0; r < 4; ++r) {
            e0[r] = __expf(fminf(fmaxf(S0T[r] - sh, -85.f), 85.f));
            e1[r] = __expf(fminf(fmaxf(S1T[r] - sh, -85.f), 85.f));
        }
        unsigned int c00 = (unsigned int)f2bf(e0[0]) | ((unsigned int)f2bf(e0[1]) << 16);
        unsigned int c01 = (unsigned int)f2bf(e0[2]) | ((unsigned int)f2bf(e0[3]) << 16);
        unsigned int c10 = (unsigned int)f2bf(e1[0]) | ((unsigned int)f2bf(e1[1]) << 16);
        unsigned int c11 = (unsigned int)f2bf(e1[2]) | ((unsigned int)f2bf(e1[3]) << 16);

        // in-register transpose: pa[j] = p[key=quad*8+j][q=l15]
        unsigned int a00 = (unsigned int)__shfl((int)c00, srcb);
        unsigned int a01 = (unsigned int)__shfl((int)c01, srcb);
        unsigned int b00 = (unsigned int)__shfl((int)c00, srcb + 16);
        unsigned int b01 = (unsigned int)__shfl((int)c01, srcb + 16);
        unsigned int a10 = (unsigned int)__shfl((int)c10, srcb);
        unsigned int a11 = (unsigned int)__shfl((int)c11, srcb);
        unsigned int b10 = (unsigned int)__shfl((int)c10, srcb + 16);
        unsigned int b11 = (unsigned int)__shfl((int)c11, srcb + 16);
        const bool sel = (quad < 2);
        union PU { unsigned int u[4]; short8 s8; } pu;
        pu.u[0] = sel ? a00 : a10;   // keys quad*8+0,1
        pu.u[1] = sel ? a01 : a11;   // +2,3
        pu.u[2] = sel ? b00 : b10;   // +4,5
        pu.u[3] = sel ? b01 : b11;   // +6,7
        short8 pa = pu.s8;

        // l accumulation: sum of this lane's 8 bf16 p values (q = l15)
        {
            float s = bf2f((unsigned short)(pu.u[0] & 0xffff)) + bf2f((unsigned short)(pu.u[0] >> 16))
                    + bf2f((unsigned short)(pu.u[1] & 0xffff)) + bf2f((unsigned short)(pu.u[1] >> 16))
                    + bf2f((unsigned short)(pu.u[2] & 0xffff)) + bf2f((unsigned short)(pu.u[2] >> 16))
                    + bf2f((unsigned short)(pu.u[3] & 0xffff)) + bf2f((unsigned short)(pu.u[3] >> 16));
            laccum += s;
        }

        // write staged phi into the other buffer
        if (kt < 63) {
            #pragma unroll
            for (int u = 0; u < 4; ++u)
                *(uint4*)(&s_ph[cur ^ 1][ldsbase + u*2112]) = stg[u];
        }

        // PV (pure-reg): O[own 16 q][all 256 cols] += P @ g
        #pragma unroll
        for (int ct = 0; ct < 16; ++ct)
            O[ct] = __builtin_amdgcn_mfma_f32_16x16x32_bf16(pa, gf[ct], O[ct], 0,0,0);

        __syncthreads();   // staging flip (also covers all S-reads of cur)
    }

    // final row sums: reduce across quads -> lane holds l[q=l15]
    laccum += __shfl_xor(laccum, 16);
    laccum += __shfl_xor(laccum, 32);
    // per-output-row reciprocal: row = quad*4+r -> take l from lane quad*4+r
    float rl[4];
    #pragma unroll
    for (int r = 0; r < 4; ++r)
        rl[r] = 1.0f / __shfl(laccum, quad*4 + r);

    // epilogue: y = O/l, out = x + y (wave's 16 rows x all 256 cols)
    #pragma unroll
    for (int ct = 0; ct < 16; ++ct) {
        #pragma unroll
        for (int r = 0; r < 4; ++r) {
            const int row = q0 + wv*16 + quad*4 + r;
            const int c   = ct*16 + l15;
            const size_t idx = (size_t)row*CC + c;
            out[idx] = x[idx] + O[ct][r] * rl[r];
        }
    }
}

// ---------------------------------------------------------------------------
extern "C" void kernel_launch(void* const* d_in, const int* in_sizes, int n_in,
                              void* d_out, int out_size, void* d_ws, size_t ws_size,
                              hipStream_t stream) {
    const float* x       = (const float*)d_in[0];
    const float* w_theta = (const float*)d_in[1];
    const float* w_phi   = (const float*)d_in[2];
    const float* w_g     = (const float*)d_in[3];
    float* out = (float*)d_out;

    // workspace (~51.2 MB)
    unsigned short* th    = (unsigned short*)d_ws;                 // fp16 16.78 MB
    unsigned short* ph    = th    + (size_t)NROWS*CC;              // fp16  8.39 MB
    unsigned short* g_f   = ph    + (size_t)PROWS*CC;              // bf16  8.39 MB (frag order)
    unsigned short* x_hi  = g_f   + (size_t)PROWS*CC;              // bf16  8.39 MB
    unsigned short* x_lo  = x_hi  + (size_t)NROWS*CC;              // bf16  8.39 MB
    unsigned short* wT_hi = x_lo  + (size_t)NROWS*CC;              // bf16  0.39 MB
    unsigned short* wT_lo = wT_hi + (size_t)3*CC*CC;               // bf16  0.39 MB
    float*          phbar = (float*)(wT_lo + (size_t)3*CC*CC);     // fp32  8 KB

    hipMemsetAsync(phbar, 0, BB*CC*sizeof(float), stream);
    xsplit_kernel<<<NROWS*CC/8/256, 256, 0, stream>>>(x, x_hi, x_lo);
    wsplit_kernel<<<dim3(4,4,3), 256, 0, stream>>>(w_theta, w_phi, w_g, wT_hi, wT_lo);
    proj_kernel<<<6144, 256, 0, stream>>>(x_hi, x_lo, wT_hi, wT_lo, th, ph, g_f);
    phimean_kernel<<<512, 256, 0, stream>>>(ph, phbar);
    attn_kernel<<<NROWS/64, 256, 0, stream>>>(x, th, ph, g_f, phbar, out);
}